// Round 2
// baseline (12244.233 us; speedup 1.0000x reference)
//
#include <hip/hip_runtime.h>
#include <stdint.h>

#define B_SZ 64
#define T_SZ 2048
#define H_SZ 256

typedef __attribute__((ext_vector_type(8))) short bf16x8_t;
typedef __attribute__((ext_vector_type(8))) _Float16 f16x8_t;
typedef __attribute__((ext_vector_type(4))) float f32x4_t;

static __device__ __forceinline__ unsigned short f2bf(float f){
  unsigned int u = __float_as_uint(f);
  return (unsigned short)((u + 0x7fffu + ((u >> 16) & 1u)) >> 16);
}
static __device__ __forceinline__ unsigned short f2h(float f){
  return __builtin_bit_cast(unsigned short, (_Float16)f);
}
static __device__ __forceinline__ float h2f(unsigned short h){
  return (float)__builtin_bit_cast(_Float16, h);
}
static __device__ __forceinline__ float sigmoidf_(float x){
  return 1.f / (1.f + __expf(-x));
}
static __device__ __forceinline__ float tanhf_(float x){
  float e = __expf(-2.f * fabsf(x));
  float t = (1.f - e) / (1.f + e);
  return copysignf(t, x);
}

// ---------- X fp32 -> bf16 (one pass; dst is the xz slot of ws) ----------
__global__ __launch_bounds__(256) void cast_x(const float* __restrict__ X,
                                              unsigned short* __restrict__ XB){
  size_t i = ((size_t)blockIdx.x*256 + threadIdx.x)*8;
  float4 v0 = *(const float4*)&X[i];
  float4 v1 = *(const float4*)&X[i+4];
  ushort4 o0; o0.x=f2bf(v0.x); o0.y=f2bf(v0.y); o0.z=f2bf(v0.z); o0.w=f2bf(v0.w);
  ushort4 o1; o1.x=f2bf(v1.x); o1.y=f2bf(v1.y); o1.z=f2bf(v1.z); o1.w=f2bf(v1.w);
  *(ushort4*)&XB[i]   = o0;
  *(ushort4*)&XB[i+4] = o1;
}

// ---------- Wi{r,z,N} fp32 -> bf16, layout [g][n][k] ----------
__global__ __launch_bounds__(256) void cast_w(const float* __restrict__ Wir,
                                              const float* __restrict__ Wiz,
                                              const float* __restrict__ WiN,
                                              unsigned short* __restrict__ WB){
  size_t i = ((size_t)blockIdx.x*256 + threadIdx.x)*8;
  int g = (int)(i >> 16);
  int rem = (int)(i & 65535);
  const float* W = (g==0) ? Wir : ((g==1) ? Wiz : WiN);
  float4 v0 = *(const float4*)&W[rem];
  float4 v1 = *(const float4*)&W[rem+4];
  ushort4 o0; o0.x=f2bf(v0.x); o0.y=f2bf(v0.y); o0.z=f2bf(v0.z); o0.w=f2bf(v0.w);
  ushort4 o1; o1.x=f2bf(v1.x); o1.y=f2bf(v1.y); o1.z=f2bf(v1.z); o1.w=f2bf(v1.w);
  *(ushort4*)&WB[i]   = o0;
  *(ushort4*)&WB[i+4] = o1;
}

// ---------- input projection: [131072,256] @ WB[g]^T, bf16 MFMA ----------
// M-tile 64, N = 256 per block. Pure bf16 staging (no conversion VALU).
__global__ __launch_bounds__(256) void proj_kernel(const unsigned short* __restrict__ XB,
                                                   const unsigned short* __restrict__ WB,
                                                   const float* __restrict__ bias,
                                                   unsigned short* __restrict__ dst16,
                                                   float* __restrict__ dst32){
  __shared__ unsigned short As[64][88];    // pad 88: 176B rows, 16B-aligned, 2-way banks
  __shared__ unsigned short Bs[256][88];
  const int tid = threadIdx.x;
  const int m0 = blockIdx.x * 64;
  const int w  = tid >> 6;
  const int l  = tid & 63;
  const int l15 = l & 15;
  const int lq  = l >> 4;

  f32x4_t acc[16];
  #pragma unroll
  for(int i = 0; i < 16; ++i) acc[i] = (f32x4_t){0.f,0.f,0.f,0.f};

  for(int kc = 0; kc < 256; kc += 64){
    #pragma unroll
    for(int p = 0; p < 2; ++p){
      int e = (p*256 + tid)*8;
      int r = e >> 6, k = e & 63;
      *(uint4*)&As[r][k] = *(const uint4*)&XB[(size_t)(m0 + r)*256 + kc + k];
    }
    #pragma unroll
    for(int p = 0; p < 8; ++p){
      int e = (p*256 + tid)*8;
      int n = e >> 6, k = e & 63;
      *(uint4*)&Bs[n][k] = *(const uint4*)&WB[n*256 + kc + k];
    }
    __syncthreads();
    #pragma unroll
    for(int ks = 0; ks < 2; ++ks){
      bf16x8_t a = *(const bf16x8_t*)&As[w*16 + l15][ks*32 + lq*8];
      #pragma unroll
      for(int fc = 0; fc < 16; ++fc){
        bf16x8_t bfr = *(const bf16x8_t*)&Bs[fc*16 + l15][ks*32 + lq*8];
        acc[fc] = __builtin_amdgcn_mfma_f32_16x16x32_bf16(a, bfr, acc[fc], 0, 0, 0);
      }
    }
    __syncthreads();
  }
  #pragma unroll
  for(int fc = 0; fc < 16; ++fc){
    int col = fc*16 + l15;
    float bv = bias[col];
    #pragma unroll
    for(int ri = 0; ri < 4; ++ri){
      int row = w*16 + lq*4 + ri;
      size_t idx = (size_t)(m0 + row)*256 + col;
      float v = acc[fc][ri] + bv;
      if(dst32) dst32[idx] = v;
      else      dst16[idx] = f2h(v);
    }
  }
}

// ---------- recurrence: MFMA scan. 4 blocks x 16 batches, 16 waves ----------
// Wave w owns cols j in [16w,16w+16) for ALL 3 gates; weights register-resident
// as f16 B-fragments (24 frags = 96 VGPR). C/D layout: row=batch, col=j, so the
// r/z/n combine is fully in-register. h double-buffered in LDS, 1 barrier/step.
__global__ __launch_bounds__(1024, 1) void scan_kernel(
    const float* __restrict__ Whr, const float* __restrict__ Whz,
    const float* __restrict__ WhN,
    const unsigned short* __restrict__ xr_all,
    const unsigned short* __restrict__ xz_all,
    float* __restrict__ out, float* __restrict__ hlast,
    const float* __restrict__ bhr, const float* __restrict__ bhz,
    const float* __restrict__ bhN){
  __shared__ _Float16 hs[2][16][264];   // pad 264: 528B rows (16B-aligned, 2-way banks)
  const int tid = threadIdx.x;
  const int w   = tid >> 6;     // 0..15 -> column block
  const int l   = tid & 63;
  const int l15 = l & 15;
  const int rq  = l >> 4;       // 0..3
  const int j   = w*16 + l15;
  const int b0  = blockIdx.x * 16;

  // load recurrent weights as f16 B-fragments: lane holds W[j][kk*32+rq*8 .. +7]
  f16x8_t wr[8], wz[8], wn[8];
  #pragma unroll
  for(int kk = 0; kk < 8; ++kk){
    const int ko = j*256 + kk*32 + rq*8;
    float4 a, b;
    a = *(const float4*)&Whr[ko]; b = *(const float4*)&Whr[ko+4];
    wr[kk] = (f16x8_t){(_Float16)a.x,(_Float16)a.y,(_Float16)a.z,(_Float16)a.w,
                       (_Float16)b.x,(_Float16)b.y,(_Float16)b.z,(_Float16)b.w};
    a = *(const float4*)&Whz[ko]; b = *(const float4*)&Whz[ko+4];
    wz[kk] = (f16x8_t){(_Float16)a.x,(_Float16)a.y,(_Float16)a.z,(_Float16)a.w,
                       (_Float16)b.x,(_Float16)b.y,(_Float16)b.z,(_Float16)b.w};
    a = *(const float4*)&WhN[ko]; b = *(const float4*)&WhN[ko+4];
    wn[kk] = (f16x8_t){(_Float16)a.x,(_Float16)a.y,(_Float16)a.z,(_Float16)a.w,
                       (_Float16)b.x,(_Float16)b.y,(_Float16)b.z,(_Float16)b.w};
  }
  const float br = bhr[j], bz = bhz[j], bn = bhN[j];

  _Float16* hflat = &hs[0][0][0];
  for(int i = tid; i < 2*16*264; i += 1024) hflat[i] = (_Float16)0.f;

  const unsigned short* xrp[4];
  const unsigned short* xzp[4];
  float* outp[4];
  float h_prev[4];
  #pragma unroll
  for(int r = 0; r < 4; ++r){
    size_t base = ((size_t)(b0 + rq*4 + r))*T_SZ*H_SZ + j;
    xrp[r] = xr_all + base;
    xzp[r] = xz_all + base;
    outp[r] = out + base;
    h_prev[r] = 0.f;
  }
  __syncthreads();

  float xrv[4], xzv[4], xnv[4];
  #pragma unroll
  for(int r = 0; r < 4; ++r){
    xrv[r] = h2f(xrp[r][0]); xzv[r] = h2f(xzp[r][0]); xnv[r] = outp[r][0];
  }

  int p = 0;
  for(int t = 0; t < T_SZ; ++t){
    // prefetch next step's projections (hides HBM latency under the MFMAs;
    // t = T-1 reads one row past end -> lands in adjacent allocated regions)
    float xrn[4], xzn[4], xnn[4];
    #pragma unroll
    for(int r = 0; r < 4; ++r){
      xrn[r] = h2f(xrp[r][H_SZ]);
      xzn[r] = h2f(xzp[r][H_SZ]);
      xnn[r] = outp[r][H_SZ];
    }
    // A-fragments of h (shared by all 3 gates)
    f16x8_t a[8];
    #pragma unroll
    for(int kk = 0; kk < 8; ++kk)
      a[kk] = *(const f16x8_t*)&hs[p][l15][kk*32 + rq*8];

    f32x4_t ar = (f32x4_t){0.f,0.f,0.f,0.f};
    f32x4_t az = (f32x4_t){0.f,0.f,0.f,0.f};
    f32x4_t an = (f32x4_t){0.f,0.f,0.f,0.f};
    #pragma unroll
    for(int kk = 0; kk < 8; ++kk){
      ar = __builtin_amdgcn_mfma_f32_16x16x32_f16(a[kk], wr[kk], ar, 0, 0, 0);
      az = __builtin_amdgcn_mfma_f32_16x16x32_f16(a[kk], wz[kk], az, 0, 0, 0);
      an = __builtin_amdgcn_mfma_f32_16x16x32_f16(a[kk], wn[kk], an, 0, 0, 0);
    }
    #pragma unroll
    for(int r = 0; r < 4; ++r){
      float rg = sigmoidf_(ar[r] + br + xrv[r]);
      float zg = sigmoidf_(az[r] + bz + xzv[r]);
      float ng = tanhf_(xnv[r] + rg*(an[r] + bn));
      float hn = ng + zg*(h_prev[r] - ng);
      h_prev[r] = hn;
      outp[r][0] = hn;
      hs[p^1][rq*4 + r][j] = (_Float16)hn;
      xrv[r] = xrn[r]; xzv[r] = xzn[r]; xnv[r] = xnn[r];
    }
    #pragma unroll
    for(int r = 0; r < 4; ++r){ xrp[r] += H_SZ; xzp[r] += H_SZ; outp[r] += H_SZ; }
    p ^= 1;
    __syncthreads();
  }
  #pragma unroll
  for(int r = 0; r < 4; ++r)
    hlast[(b0 + rq*4 + r)*H_SZ + j] = h_prev[r];
}

extern "C" void kernel_launch(void* const* d_in, const int* in_sizes, int n_in,
                              void* d_out, int out_size, void* d_ws, size_t ws_size,
                              hipStream_t stream){
  const float* X   = (const float*)d_in[0];
  const float* Wir = (const float*)d_in[1];
  const float* bir = (const float*)d_in[2];
  const float* Whr = (const float*)d_in[3];
  const float* bhr = (const float*)d_in[4];
  const float* Wiz = (const float*)d_in[5];
  const float* biz = (const float*)d_in[6];
  const float* Whz = (const float*)d_in[7];
  const float* bhz = (const float*)d_in[8];
  const float* WiN = (const float*)d_in[9];
  const float* biN = (const float*)d_in[10];
  const float* WhN = (const float*)d_in[11];
  const float* bhN = (const float*)d_in[12];

  float* out   = (float*)d_out;
  float* hlast = out + (size_t)B_SZ*T_SZ*H_SZ;

  unsigned char* ws = (unsigned char*)d_ws;
  const size_t XN = (size_t)B_SZ*T_SZ*H_SZ;           // 33,554,432
  unsigned short* xr = (unsigned short*)ws;            // 67.1 MB f16
  unsigned short* xz = (unsigned short*)(ws + XN*2);   // 67.1 MB: bf16 X first, f16 xz after
  unsigned short* WB = (unsigned short*)(ws + XN*4);   // 384 KB bf16 input weights
  unsigned short* XB = xz;                             // bf16 X lives in the xz slot

  cast_w<<<96, 256, 0, stream>>>(Wir, Wiz, WiN, WB);
  cast_x<<<16384, 256, 0, stream>>>(X, XB);
  proj_kernel<<<2048, 256, 0, stream>>>(XB, WB,           bir, xr, nullptr);
  proj_kernel<<<2048, 256, 0, stream>>>(XB, WB + 2*65536, biN, nullptr, out);  // xn fp32 -> d_out
  // z LAST: writes xz in place over XB (each block reads its whole A-tile
  // before its epilogue writes the same flat range; tiles are disjoint).
  proj_kernel<<<2048, 256, 0, stream>>>(XB, WB + 65536,   biz, xz, nullptr);
  scan_kernel<<<4, 1024, 0, stream>>>(Whr, Whz, WhN, xr, xz, out, hlast, bhr, bhz, bhN);
}

// Round 3
// 5934.356 us; speedup vs baseline: 2.0633x; 2.0633x over previous
//
#include <hip/hip_runtime.h>
#include <stdint.h>

#define B_SZ 64
#define T_SZ 2048
#define H_SZ 256
#define TH   (T_SZ * H_SZ)

typedef __attribute__((ext_vector_type(8))) short bf16x8_t;
typedef __attribute__((ext_vector_type(8))) _Float16 f16x8_t;
typedef __attribute__((ext_vector_type(4))) float f32x4_t;

static __device__ __forceinline__ unsigned short f2bf(float f){
  unsigned int u = __float_as_uint(f);
  return (unsigned short)((u + 0x7fffu + ((u >> 16) & 1u)) >> 16);
}
static __device__ __forceinline__ unsigned short f2h(float f){
  return __builtin_bit_cast(unsigned short, (_Float16)f);
}
static __device__ __forceinline__ float h2f(unsigned short h){
  return (float)__builtin_bit_cast(_Float16, h);
}
static __device__ __forceinline__ float sigmoidf_(float x){
  return 1.f / (1.f + __expf(-x));
}
static __device__ __forceinline__ float tanhf_(float x){
  float e = __expf(-2.f * fabsf(x));
  float t = (1.f - e) / (1.f + e);
  return copysignf(t, x);
}
// global -> LDS async DMA, 16B per lane; dest = wave-uniform base + lane*16
static __device__ __forceinline__ void stage16(const void* g, void* l){
  __builtin_amdgcn_global_load_lds(
      (const __attribute__((address_space(1))) unsigned int*)g,
      (__attribute__((address_space(3))) unsigned int*)l, 16, 0, 0);
}

// ---------- X fp32 -> bf16 (dst aliases the xz slot of ws) ----------
__global__ __launch_bounds__(256) void cast_x(const float* __restrict__ X,
                                              unsigned short* __restrict__ XB){
  size_t i = ((size_t)blockIdx.x*256 + threadIdx.x)*8;
  float4 v0 = *(const float4*)&X[i];
  float4 v1 = *(const float4*)&X[i+4];
  ushort4 o0; o0.x=f2bf(v0.x); o0.y=f2bf(v0.y); o0.z=f2bf(v0.z); o0.w=f2bf(v0.w);
  ushort4 o1; o1.x=f2bf(v1.x); o1.y=f2bf(v1.y); o1.z=f2bf(v1.z); o1.w=f2bf(v1.w);
  *(ushort4*)&XB[i]   = o0;
  *(ushort4*)&XB[i+4] = o1;
}

// ---------- Wi{r,z,N} fp32 -> bf16, layout [g][n][k] ----------
__global__ __launch_bounds__(256) void cast_w(const float* __restrict__ Wir,
                                              const float* __restrict__ Wiz,
                                              const float* __restrict__ WiN,
                                              unsigned short* __restrict__ WB){
  size_t i = ((size_t)blockIdx.x*256 + threadIdx.x)*8;
  int g = (int)(i >> 16);
  int rem = (int)(i & 65535);
  const float* W = (g==0) ? Wir : ((g==1) ? Wiz : WiN);
  float4 v0 = *(const float4*)&W[rem];
  float4 v1 = *(const float4*)&W[rem+4];
  ushort4 o0; o0.x=f2bf(v0.x); o0.y=f2bf(v0.y); o0.z=f2bf(v0.z); o0.w=f2bf(v0.w);
  ushort4 o1; o1.x=f2bf(v1.x); o1.y=f2bf(v1.y); o1.z=f2bf(v1.z); o1.w=f2bf(v1.w);
  *(ushort4*)&WB[i]   = o0;
  *(ushort4*)&WB[i+4] = o1;
}

// ---------- input projection: [131072,256] @ WB[g]^T, bf16 MFMA ----------
// bias2 (recurrent bias) folded in where legal (r,z gates).
__global__ __launch_bounds__(256) void proj_kernel(const unsigned short* __restrict__ XB,
                                                   const unsigned short* __restrict__ WB,
                                                   const float* __restrict__ bias,
                                                   const float* __restrict__ bias2,
                                                   unsigned short* __restrict__ dst16,
                                                   float* __restrict__ dst32){
  __shared__ unsigned short As[64][88];
  __shared__ unsigned short Bs[256][88];
  const int tid = threadIdx.x;
  const int m0 = blockIdx.x * 64;
  const int w  = tid >> 6;
  const int l  = tid & 63;
  const int l15 = l & 15;
  const int lq  = l >> 4;

  f32x4_t acc[16];
  #pragma unroll
  for(int i = 0; i < 16; ++i) acc[i] = (f32x4_t){0.f,0.f,0.f,0.f};

  for(int kc = 0; kc < 256; kc += 64){
    #pragma unroll
    for(int p = 0; p < 2; ++p){
      int e = (p*256 + tid)*8;
      int r = e >> 6, k = e & 63;
      *(uint4*)&As[r][k] = *(const uint4*)&XB[(size_t)(m0 + r)*256 + kc + k];
    }
    #pragma unroll
    for(int p = 0; p < 8; ++p){
      int e = (p*256 + tid)*8;
      int n = e >> 6, k = e & 63;
      *(uint4*)&Bs[n][k] = *(const uint4*)&WB[n*256 + kc + k];
    }
    __syncthreads();
    #pragma unroll
    for(int ks = 0; ks < 2; ++ks){
      bf16x8_t a = *(const bf16x8_t*)&As[w*16 + l15][ks*32 + lq*8];
      #pragma unroll
      for(int fc = 0; fc < 16; ++fc){
        bf16x8_t bfr = *(const bf16x8_t*)&Bs[fc*16 + l15][ks*32 + lq*8];
        acc[fc] = __builtin_amdgcn_mfma_f32_16x16x32_bf16(a, bfr, acc[fc], 0, 0, 0);
      }
    }
    __syncthreads();
  }
  #pragma unroll
  for(int fc = 0; fc < 16; ++fc){
    int col = fc*16 + l15;
    float bv = bias[col] + (bias2 ? bias2[col] : 0.f);
    #pragma unroll
    for(int ri = 0; ri < 4; ++ri){
      int row = w*16 + lq*4 + ri;
      size_t idx = (size_t)(m0 + row)*256 + col;
      float v = acc[fc][ri] + bv;
      if(dst32) dst32[idx] = v;
      else      dst16[idx] = f2h(v);
    }
  }
}

// ---------- recurrence: MFMA scan, 4 blocks x 16 batches, 8 waves ----------
// D = W (A, rows=j) x h^T (B, cols=batch). Lane: b = l&15, j-runs of 4.
// Weights register-resident (192 VGPR). x staged 1 step ahead via
// global_load_lds with 16B XOR source-swizzle (read applies same XOR).
__global__ __launch_bounds__(512, 2) void scan_kernel(
    const float* __restrict__ Whr, const float* __restrict__ Whz,
    const float* __restrict__ WhN,
    const unsigned short* __restrict__ xr_g,
    const unsigned short* __restrict__ xz_g,
    float* __restrict__ out, float* __restrict__ hlast,
    const float* __restrict__ bhN){
  __shared__ _Float16 hs[2][16][264];                // h, row-major [b][k]
  __shared__ __align__(16) _Float16 xr_sh[2][16][256];
  __shared__ __align__(16) _Float16 xz_sh[2][16][256];
  __shared__ __align__(16) float    xn_sh[2][16][256];
  __shared__ float bhn_s[256];

  const int tid  = threadIdx.x;
  const int w    = tid >> 6;      // wave 0..7: owns j in [32w, 32w+32)
  const int l    = tid & 63;
  const int l15  = l & 15;        // = batch b (D col)
  const int rq   = l >> 4;
  const int half = l >> 5;
  const int l31  = l & 31;
  const int b0   = blockIdx.x * 16;

  // ---- load recurrent weights as A-fragments (f16), 192 VGPRs ----
  f16x8_t Wr[2][8], Wz[2][8], Wn[2][8];
  #pragma unroll
  for(int jt = 0; jt < 2; ++jt){
    const int j = w*32 + jt*16 + l15;
    #pragma unroll
    for(int kk = 0; kk < 8; ++kk){
      const int ko = j*256 + kk*32 + rq*8;
      float4 a, b;
      a = *(const float4*)&Whr[ko]; b = *(const float4*)&Whr[ko+4];
      Wr[jt][kk] = (f16x8_t){(_Float16)a.x,(_Float16)a.y,(_Float16)a.z,(_Float16)a.w,
                             (_Float16)b.x,(_Float16)b.y,(_Float16)b.z,(_Float16)b.w};
      a = *(const float4*)&Whz[ko]; b = *(const float4*)&Whz[ko+4];
      Wz[jt][kk] = (f16x8_t){(_Float16)a.x,(_Float16)a.y,(_Float16)a.z,(_Float16)a.w,
                             (_Float16)b.x,(_Float16)b.y,(_Float16)b.z,(_Float16)b.w};
      a = *(const float4*)&WhN[ko]; b = *(const float4*)&WhN[ko+4];
      Wn[jt][kk] = (f16x8_t){(_Float16)a.x,(_Float16)a.y,(_Float16)a.z,(_Float16)a.w,
                             (_Float16)b.x,(_Float16)b.y,(_Float16)b.z,(_Float16)b.w};
    }
  }

  for(int i = tid; i < 2*16*264; i += 512) ((_Float16*)hs)[i] = (_Float16)0.f;
  if(tid < 256) bhn_s[tid] = bhN[tid];

  // ---- stage t=0 into buf 0 ----
  {
    const int bb = 2*w + half;
    const size_t rb = ((size_t)(b0 + bb)*T_SZ + 0)*H_SZ;
    const int so = (l31*16) ^ ((bb & 7) << 4);
    stage16((const char*)xr_g + rb*2 + so, &xr_sh[0][2*w][0]);
    stage16((const char*)xz_g + rb*2 + so, &xz_sh[0][2*w][0]);
    #pragma unroll
    for(int i = 0; i < 2; ++i){
      const int bn_ = w + 8*i;
      const size_t rn = ((size_t)(b0 + bn_)*T_SZ + 0)*H_SZ;
      stage16((const char*)out + rn*4 + ((l*16) ^ ((bn_ & 7) << 4)), &xn_sh[0][bn_][0]);
    }
  }
  __syncthreads();

  for(int t = 0; t < T_SZ; ++t){
    const int pb = t & 1;
    // ---- stage t+1 into buf pb^1 (async; drained by the end-of-step barrier) ----
    if(t + 1 < T_SZ){
      const int t1 = t + 1;
      const int bb = 2*w + half;
      const size_t rb = ((size_t)(b0 + bb)*T_SZ + t1)*H_SZ;
      const int so = (l31*16) ^ ((bb & 7) << 4);
      stage16((const char*)xr_g + rb*2 + so, &xr_sh[pb^1][2*w][0]);
      stage16((const char*)xz_g + rb*2 + so, &xz_sh[pb^1][2*w][0]);
      #pragma unroll
      for(int i = 0; i < 2; ++i){
        const int bn_ = w + 8*i;
        const size_t rn = ((size_t)(b0 + bn_)*T_SZ + t1)*H_SZ;
        stage16((const char*)out + rn*4 + ((l*16) ^ ((bn_ & 7) << 4)), &xn_sh[pb^1][bn_][0]);
      }
    }

    // ---- MFMA: D[j, b] accumulate; n-gate C-init = bhN ----
    f32x4_t ar0={0,0,0,0}, ar1={0,0,0,0}, az0={0,0,0,0}, az1={0,0,0,0};
    f32x4_t an0 = *(const f32x4_t*)&bhn_s[w*32 + rq*4];
    f32x4_t an1 = *(const f32x4_t*)&bhn_s[w*32 + 16 + rq*4];
    #pragma unroll
    for(int kk = 0; kk < 8; ++kk){
      f16x8_t hq = *(const f16x8_t*)&hs[pb][l15][kk*32 + rq*8];
      ar0 = __builtin_amdgcn_mfma_f32_16x16x32_f16(Wr[0][kk], hq, ar0, 0, 0, 0);
      az0 = __builtin_amdgcn_mfma_f32_16x16x32_f16(Wz[0][kk], hq, az0, 0, 0, 0);
      an0 = __builtin_amdgcn_mfma_f32_16x16x32_f16(Wn[0][kk], hq, an0, 0, 0, 0);
      ar1 = __builtin_amdgcn_mfma_f32_16x16x32_f16(Wr[1][kk], hq, ar1, 0, 0, 0);
      az1 = __builtin_amdgcn_mfma_f32_16x16x32_f16(Wz[1][kk], hq, az1, 0, 0, 0);
      an1 = __builtin_amdgcn_mfma_f32_16x16x32_f16(Wn[1][kk], hq, an1, 0, 0, 0);
    }

    // ---- epilogue: vectorized LDS reads, in-register gate combine ----
    const int swz = (l15 & 7) << 4;
    #pragma unroll
    for(int cb = 0; cb < 2; ++cb){
      const int jb = w*32 + cb*16 + rq*4;
      ushort4 xr4 = *(const ushort4*)((const char*)xr_sh + pb*8192  + l15*512  + ((jb*2) ^ swz));
      ushort4 xz4 = *(const ushort4*)((const char*)xz_sh + pb*8192  + l15*512  + ((jb*2) ^ swz));
      float4  xn4 = *(const float4*) ((const char*)xn_sh + pb*16384 + l15*1024 + ((jb*4) ^ swz));
      ushort4 hp4 = *(const ushort4*)((const char*)hs    + pb*8448  + l15*528  + jb*2);
      float arx[4] = { (cb ? ar1 : ar0)[0], (cb ? ar1 : ar0)[1], (cb ? ar1 : ar0)[2], (cb ? ar1 : ar0)[3] };
      float azx[4] = { (cb ? az1 : az0)[0], (cb ? az1 : az0)[1], (cb ? az1 : az0)[2], (cb ? az1 : az0)[3] };
      float anx[4] = { (cb ? an1 : an0)[0], (cb ? an1 : an0)[1], (cb ? an1 : an0)[2], (cb ? an1 : an0)[3] };
      const unsigned short* xrp = (const unsigned short*)&xr4;
      const unsigned short* xzp = (const unsigned short*)&xz4;
      const unsigned short* hpp = (const unsigned short*)&hp4;
      const float* xnp = (const float*)&xn4;
      float4 hn4; float* hnp = (float*)&hn4;
      #pragma unroll
      for(int ri = 0; ri < 4; ++ri){
        float rg = sigmoidf_(arx[ri] + h2f(xrp[ri]));
        float zg = sigmoidf_(azx[ri] + h2f(xzp[ri]));
        float ng = tanhf_(xnp[ri] + rg*anx[ri]);
        float hp = h2f(hpp[ri]);
        hnp[ri] = ng + zg*(hp - ng);
      }
      *(float4*)&out[(size_t)(b0 + l15)*TH + (size_t)t*H_SZ + jb] = hn4;
      ushort4 hw; hw.x = f2h(hnp[0]); hw.y = f2h(hnp[1]); hw.z = f2h(hnp[2]); hw.w = f2h(hnp[3]);
      *(ushort4*)((char*)hs + (pb^1)*8448 + l15*528 + jb*2) = hw;
    }
    __syncthreads();
  }

  // final h lives in hs[0] (t=2047 wrote buf 0)
  #pragma unroll
  for(int cb = 0; cb < 2; ++cb){
    const int jb = w*32 + cb*16 + rq*4;
    ushort4 hf = *(const ushort4*)((const char*)hs + l15*528 + jb*2);
    float4 o; o.x = h2f(hf.x); o.y = h2f(hf.y); o.z = h2f(hf.z); o.w = h2f(hf.w);
    *(float4*)&hlast[(size_t)(b0 + l15)*H_SZ + jb] = o;
  }
}

extern "C" void kernel_launch(void* const* d_in, const int* in_sizes, int n_in,
                              void* d_out, int out_size, void* d_ws, size_t ws_size,
                              hipStream_t stream){
  const float* X   = (const float*)d_in[0];
  const float* Wir = (const float*)d_in[1];
  const float* bir = (const float*)d_in[2];
  const float* Whr = (const float*)d_in[3];
  const float* bhr = (const float*)d_in[4];
  const float* Wiz = (const float*)d_in[5];
  const float* biz = (const float*)d_in[6];
  const float* Whz = (const float*)d_in[7];
  const float* bhz = (const float*)d_in[8];
  const float* WiN = (const float*)d_in[9];
  const float* biN = (const float*)d_in[10];
  const float* WhN = (const float*)d_in[11];
  const float* bhN = (const float*)d_in[12];

  float* out   = (float*)d_out;
  float* hlast = out + (size_t)B_SZ*TH;

  unsigned char* ws = (unsigned char*)d_ws;
  const size_t XN = (size_t)B_SZ*TH;                 // 33,554,432
  unsigned short* xr = (unsigned short*)ws;          // 67.1 MB f16
  unsigned short* xz = (unsigned short*)(ws + XN*2); // 67.1 MB (bf16 X first, xz after)
  unsigned short* WB = (unsigned short*)(ws + XN*4); // 384 KB bf16 input weights
  unsigned short* XB = xz;                           // bf16 X aliases the xz slot

  cast_w<<<96, 256, 0, stream>>>(Wir, Wiz, WiN, WB);
  cast_x<<<16384, 256, 0, stream>>>(X, XB);
  // r-gate: fold bhr; n-gate: fp32 xn -> d_out (bhN handled in scan C-init)
  proj_kernel<<<2048, 256, 0, stream>>>(XB, WB,           bir, bhr,     xr, nullptr);
  proj_kernel<<<2048, 256, 0, stream>>>(XB, WB + 2*65536, biN, nullptr, nullptr, out);
  // z LAST: writes xz in place over XB (block reads whole A-tile before epilogue)
  proj_kernel<<<2048, 256, 0, stream>>>(XB, WB + 65536,   biz, bhz,     xz, nullptr);
  scan_kernel<<<4, 512, 0, stream>>>(Whr, Whz, WhN, xr, xz, out, hlast, bhN);
}